// Round 5
// baseline (5706.856 us; speedup 1.0000x reference)
//
#include <hip/hip_runtime.h>
#include <math.h>

#define BATCH 1024
#define SEQ   256
#define UNITS 256
#define NC    128

typedef __attribute__((ext_vector_type(8))) short  short8;   // 8 bf16 = 4 VGPRs
typedef __attribute__((ext_vector_type(4))) float  float4v;  // MFMA C/D

// Gate math (validated r1-r4: absmax 6.1e-5 vs 1.72e-4 threshold)
__device__ __forceinline__ float sigf(float x)  { return 1.f / (1.f + __expf(-x)); }
__device__ __forceinline__ float tanhf_(float x){ return 1.f - 2.f / (1.f + __expf(2.f * x)); }

__device__ __forceinline__ unsigned short bf16rne(float f) {
    unsigned u = __float_as_uint(f);
    return (unsigned short)((u + 0x7fffu + ((u >> 16) & 1u)) >> 16);
}
__device__ __forceinline__ float bf16tof(unsigned short s) {
    return __uint_as_float(((unsigned)s) << 16);
}

// ---------------------------------------------------------------------------
// prep: Rp[ui][sp][g][kc][lane][8] bf16-split B-frag layout (per-block 64KB
//       contiguous, lane-linear for conflict-free LDS use);
//       Wkb[ch][u*4+g] fp32 with bias folded; zero H0A/H1A; zero counters.
__global__ __launch_bounds__(256) void prep(
    const float* __restrict__ R, const float* __restrict__ Wk,
    const float* __restrict__ bias,
    unsigned short* __restrict__ Rp, float* __restrict__ Wkb,
    unsigned short* __restrict__ H0A, unsigned short* __restrict__ H1A,
    unsigned* __restrict__ ctr)
{
    int i = blockIdx.x * 256 + threadIdx.x;   // 0..524287
    int j    = i & 7;
    int lane = (i >> 3) & 63;
    int kc   = (i >> 9) & 7;
    int g    = (i >> 12) & 3;
    int sp   = (i >> 14) & 1;
    int ui   = i >> 15;
    int u = ui * 16 + (lane & 15);
    int k = kc * 32 + (lane >> 4) * 8 + j;
    float v = R[k * 1024 + g * 256 + u];
    unsigned short r0 = bf16rne(v);
    Rp[i] = sp ? bf16rne(v - bf16tof(r0)) : r0;
    if (i < 131072) {
        int r = i & 1023;
        int uu = r >> 2, gg = r & 3;
        int src = (gg << 8) + uu;
        Wkb[i] = Wk[(i >> 10) * 1024 + src] + bias[src];
        ((unsigned*)H0A)[i] = 0;   // 131072 u32 = 262144 ushorts
        ((unsigned*)H1A)[i] = 0;
    }
    if (i < 64) ctr[i] = 0;
}

// ---------------------------------------------------------------------------
// Persistent LSTM. Grid 256 x 128 thr (2 waves). Block (bi = batch group of
// 64, ui = unit group of 16). R-slice LDS-resident for all 256 steps; c in
// registers; h bf16-split ping-pong in global; row barrier over the 16
// blocks sharing bi (threadfence + atomic counter, monotone target).
// Wave wv owns 32 batches (2 m-tiles); round-4 MFMA fragment mapping.
__global__ __launch_bounds__(128, 1) void lstm_persist(
    const unsigned short* __restrict__ Rp, const float* __restrict__ Wkb,
    const int* __restrict__ inp,
    unsigned short* __restrict__ H0A, unsigned short* __restrict__ H1A,
    unsigned short* __restrict__ H0B, unsigned short* __restrict__ H1B,
    unsigned* __restrict__ ctr)
{
    __shared__ unsigned short Rl[32768];   // 64KB: [sp][g][kc][lane][8]

    const int tid  = threadIdx.x;
    const int lane = tid & 63;
    const int wv   = tid >> 6;            // 0..1
    const int bi   = blockIdx.x & 15;     // batch row group (64 batches)
    const int ui   = blockIdx.x >> 4;     // unit col group (16 units)
    const int nl   = lane & 15;
    const int quad = lane >> 4;
    const int u    = ui * 16 + nl;        // lane's unit
    const int b0w  = bi * 64 + wv * 32;   // wave's 32-batch base

    // Stage R slice once: 64KB contiguous from Rp + ui*32768 ushorts.
    {
        const float4* src = (const float4*)(Rp + (ui << 15));
        float4* dst = (float4*)Rl;
#pragma unroll
        for (int it = 0; it < 32; it++)
            dst[tid + (it << 7)] = src[tid + (it << 7)];
    }
    __syncthreads();

    float c[2][4];
#pragma unroll
    for (int mt = 0; mt < 2; mt++)
#pragma unroll
        for (int r = 0; r < 4; r++) c[mt][r] = 0.f;

    const int arow = (b0w + nl) * 256 + (quad << 3);   // A-frag base (ushorts)

    for (int t = 0; t < SEQ; t++) {
        const unsigned short* H0in = (t & 1) ? H0B : H0A;
        const unsigned short* H1in = (t & 1) ? H1B : H1A;
        unsigned short* H0out = (t & 1) ? H0A : H0B;
        unsigned short* H1out = (t & 1) ? H1A : H1B;

        // A-frags: 32 x 16B global loads, all issued up front.
        short8 a[2][2][8];   // [mt][sp][kc]
#pragma unroll
        for (int mt = 0; mt < 2; mt++)
#pragma unroll
            for (int kc = 0; kc < 8; kc++) {
                a[mt][0][kc] = *(const short8*)&H0in[arow + mt * 4096 + kc * 32];
                a[mt][1][kc] = *(const short8*)&H1in[arow + mt * 4096 + kc * 32];
            }

        // inp gather for epilogue (8 batches per lane).
        int ch[2][4];
#pragma unroll
        for (int mt = 0; mt < 2; mt++)
#pragma unroll
            for (int r = 0; r < 4; r++)
                ch[mt][r] = inp[(b0w + mt * 16 + (quad << 2) + r) * SEQ + t];

        float4v acc[2][4];
#pragma unroll
        for (int mt = 0; mt < 2; mt++)
#pragma unroll
            for (int g = 0; g < 4; g++)
                acc[mt][g] = (float4v){0.f, 0.f, 0.f, 0.f};

#pragma unroll
        for (int kc = 0; kc < 8; kc++) {
#pragma unroll
            for (int g = 0; g < 4; g++) {
                short8 b0 = *(const short8*)&Rl[((g << 3) + kc) * 512 + (lane << 3)];
                short8 b1 = *(const short8*)&Rl[((g << 3) + kc) * 512 + 16384 + (lane << 3)];
#pragma unroll
                for (int mt = 0; mt < 2; mt++) {
                    acc[mt][g] = __builtin_amdgcn_mfma_f32_16x16x32_bf16(a[mt][0][kc], b0, acc[mt][g], 0, 0, 0);
                    acc[mt][g] = __builtin_amdgcn_mfma_f32_16x16x32_bf16(a[mt][1][kc], b0, acc[mt][g], 0, 0, 0);
                    acc[mt][g] = __builtin_amdgcn_mfma_f32_16x16x32_bf16(a[mt][0][kc], b1, acc[mt][g], 0, 0, 0);
                    acc[mt][g] = __builtin_amdgcn_mfma_f32_16x16x32_bf16(a[mt][1][kc], b1, acc[mt][g], 0, 0, 0);
                }
            }
        }

        // Epilogue: 8 (batch,unit) states per lane.
#pragma unroll
        for (int mt = 0; mt < 2; mt++)
#pragma unroll
            for (int r = 0; r < 4; r++) {
                const int be = b0w + mt * 16 + (quad << 2) + r;
                float4v wk = *(const float4v*)&Wkb[(ch[mt][r] << 10) + (u << 2)];
                float zi = acc[mt][0][r] + wk.x;
                float zf = acc[mt][1][r] + wk.y;
                float zg = acc[mt][2][r] + wk.z;
                float zo = acc[mt][3][r] + wk.w;
                float ig = sigf(zi), fg = sigf(zf), gg = tanhf_(zg), og = sigf(zo);
                float cn = fg * c[mt][r] + ig * gg;
                c[mt][r] = cn;
                float hv = og * tanhf_(cn);
                unsigned short h0 = bf16rne(hv);
                unsigned short h1 = bf16rne(hv - bf16tof(h0));
                H0out[be * 256 + u] = h0;
                H1out[be * 256 + u] = h1;
            }

        // Row barrier: the 16 blocks sharing bi exchange h. Monotone target,
        // all 256 blocks co-resident (1/CU by LDS) -> no deadlock.
        if (t != SEQ - 1) {
            __syncthreads();               // drains vmcnt: all stores issued
            if (tid == 0) {
                __threadfence();           // release: L2 writeback
                atomicAdd(&ctr[bi], 1u);
                const unsigned target = (unsigned)(t + 1) * 16u;
                while (__hip_atomic_load(&ctr[bi], __ATOMIC_RELAXED,
                                         __HIP_MEMORY_SCOPE_AGENT) < target)
                    __builtin_amdgcn_s_sleep(2);
                __threadfence();           // acquire: invalidate L1/L2
            }
            __syncthreads();
        }
    }
}

// ---------------------------------------------------------------------------
// logits = h_last @ dense_w + dense_b ; softmax. h reconstructed = h0 + h1.
__global__ __launch_bounds__(128) void dense_softmax(
    const unsigned short* __restrict__ H0, const unsigned short* __restrict__ H1,
    const float* __restrict__ W, const float* __restrict__ b,
    float* __restrict__ out)
{
    __shared__ float hsr[UNITS];
    __shared__ float red[NC];
    const int bq = blockIdx.x;
    const int n  = threadIdx.x;

    hsr[n]       = bf16tof(H0[bq * 256 + n])       + bf16tof(H1[bq * 256 + n]);
    hsr[n + 128] = bf16tof(H0[bq * 256 + n + 128]) + bf16tof(H1[bq * 256 + n + 128]);
    __syncthreads();

    float acc = b[n];
#pragma unroll 8
    for (int k = 0; k < UNITS; k++) acc += hsr[k] * W[k * NC + n];

    red[n] = acc;
    __syncthreads();
    for (int s = 64; s > 0; s >>= 1) {
        if (n < s) red[n] = fmaxf(red[n], red[n + s]);
        __syncthreads();
    }
    float m = red[0];
    __syncthreads();

    float e = __expf(acc - m);
    red[n] = e;
    __syncthreads();
    for (int s = 64; s > 0; s >>= 1) {
        if (n < s) red[n] = red[n] + red[n + s];
        __syncthreads();
    }
    out[bq * NC + n] = e / red[0];
}

// ---------------------------------------------------------------------------
extern "C" void kernel_launch(void* const* d_in, const int* in_sizes, int n_in,
                              void* d_out, int out_size, void* d_ws, size_t ws_size,
                              hipStream_t stream)
{
    const int*   inp  = (const int*)d_in[0];    // [1024][256]
    const float* Wk   = (const float*)d_in[1];  // [128][1024]
    const float* R    = (const float*)d_in[2];  // [256][1024]
    const float* bias = (const float*)d_in[3];  // [1024]
    const float* Wd   = (const float*)d_in[4];  // [256][128]
    const float* bd   = (const float*)d_in[5];  // [128]
    float* out = (float*)d_out;

    // ws: Rp (1MB) | Wkb (512KB) | H0A|H1A|H0B|H1B (512KB ea) | ctr
    unsigned short* Rp  = (unsigned short*)d_ws;
    float*          Wkb = (float*)(Rp + 524288);
    unsigned short* H0A = (unsigned short*)(Wkb + 131072);
    unsigned short* H1A = H0A + 262144;
    unsigned short* H0B = H1A + 262144;
    unsigned short* H1B = H0B + 262144;
    unsigned*       ctr = (unsigned*)(H1B + 262144);

    prep<<<dim3(2048), dim3(256), 0, stream>>>(R, Wk, bias, Rp, Wkb, H0A, H1A, ctr);

    lstm_persist<<<dim3(256), dim3(128), 0, stream>>>(Rp, Wkb, inp,
                                                      H0A, H1A, H0B, H1B, ctr);

    // t=255 (odd) wrote the A set
    dense_softmax<<<dim3(BATCH), dim3(128), 0, stream>>>(H0A, H1A, Wd, bd, out);
}

// Round 6
// 1893.370 us; speedup vs baseline: 3.0141x; 3.0141x over previous
//
#include <hip/hip_runtime.h>
#include <math.h>

#define BATCH 1024
#define SEQ   256
#define UNITS 256
#define NC    128

typedef __attribute__((ext_vector_type(8))) short  short8;   // 8 bf16 = 4 VGPRs
typedef __attribute__((ext_vector_type(4))) float  float4v;  // MFMA C/D
typedef unsigned long long u64;
typedef unsigned int       u32;

// Gate math (validated r1-r5: absmax 6.1e-5 vs 1.72e-4 threshold)
__device__ __forceinline__ float sigf(float x)  { return 1.f / (1.f + __expf(-x)); }
__device__ __forceinline__ float tanhf_(float x){ return 1.f - 2.f / (1.f + __expf(2.f * x)); }

__device__ __forceinline__ unsigned short bf16rne(float f) {
    unsigned u = __float_as_uint(f);
    return (unsigned short)((u + 0x7fffu + ((u >> 16) & 1u)) >> 16);
}
__device__ __forceinline__ float bf16tof(unsigned short s) {
    return __uint_as_float(((unsigned)s) << 16);
}

// ---------------------------------------------------------------------------
// prep: R0t/R1t[col][k] bf16 split (col = g*256+u, r4-verified layout);
//       Wkb[ch][u*4+g] = Wk + bias (gate-packed); H01A zeroed; ctr zeroed.
__global__ __launch_bounds__(256) void prep(
    const float* __restrict__ R, const float* __restrict__ Wk,
    const float* __restrict__ bias,
    unsigned short* __restrict__ R0t, unsigned short* __restrict__ R1t,
    float* __restrict__ Wkb, u32* __restrict__ H01A, u32* __restrict__ ctr)
{
    int i = blockIdx.x * 256 + threadIdx.x;    // 0..262143
    int col = i >> 8, k = i & 255;
    float v = R[k * 1024 + col];
    unsigned short r0 = bf16rne(v);
    R0t[i] = r0;
    R1t[i] = bf16rne(v - bf16tof(r0));
    H01A[i] = 0u;                              // h_0 = 0 (packed)
    if (i < NC * 1024) {
        int r = i & 1023;
        int u = r >> 2, g = r & 3;
        int src = (g << 8) + u;
        Wkb[i] = Wk[(i >> 10) * 1024 + src] + bias[src];
    }
    if (i < 16) ctr[i] = 0u;
}

// ---------------------------------------------------------------------------
// Persistent LSTM, fence-free. Grid 256 x 256 thr (4 waves, <=1 block/CU ->
// all resident, no deadlock). Block (bi=64 batches, ui=16 units), XCD-swizzled
// so the 16 blocks of a row share an XCD (perf-only assumption). Wave wv owns
// 16 batches. R B-frags live in VGPRs for all 256 steps (no LDS, no R
// traffic). h is a packed u32 (h1<<16|h0) exchanged ONLY via device-scope
// relaxed atomics (coherent at L3 -> no threadfence, no L2 flush/inv).
// Row barrier: atomic counter, monotone target; h-store visibility before the
// counter bump is guaranteed by the pre-s_barrier vmcnt drain.
__global__ __launch_bounds__(256, 1) void lstm_persist(
    const unsigned short* __restrict__ R0t, const unsigned short* __restrict__ R1t,
    const float* __restrict__ Wkb, const int* __restrict__ inp,
    u32* __restrict__ H01A, u32* __restrict__ H01B, u32* __restrict__ ctr)
{
    const int tid  = threadIdx.x;
    const int lane = tid & 63;
    const int wv   = tid >> 6;                           // 0..3
    const int bi   = ((blockIdx.x & 7) << 1) | (blockIdx.x >> 7);   // 0..15
    const int ui   = (blockIdx.x >> 3) & 15;             // 0..15
    const int nl   = lane & 15;
    const int quad = lane >> 4;
    const int u    = ui * 16 + nl;                       // lane's unit
    const int bm   = bi * 64 + wv * 16;                  // wave's 16-batch base
    const int be   = bm + (quad << 2);                   // lane's 4-batch base

    // Hoist all B-frags (r4-verified mapping) into registers: 64 x short8.
    short8 B0[4][8], B1[4][8];
#pragma unroll
    for (int g = 0; g < 4; g++)
#pragma unroll
        for (int kt = 0; kt < 8; kt++) {
            const int idx = ((g << 8) + u) * 256 + (kt << 5) + (quad << 3);
            B0[g][kt] = *(const short8*)&R0t[idx];
            B1[g][kt] = *(const short8*)&R1t[idx];
        }

    float c[4] = {0.f, 0.f, 0.f, 0.f};
    const int arow = (bm + nl) * 256 + (quad << 3);      // A-frag u32 base

    for (int t = 0; t < SEQ; t++) {
        const u32* H01in = (t & 1) ? H01B : H01A;
        u32*       H01out = (t & 1) ? H01A : H01B;

        // A-frags: 32 atomic u64 loads (device-coherent, bypass stale L1/L2).
        u64 q[8][4];
#pragma unroll
        for (int kt = 0; kt < 8; kt++) {
            const u64* p = (const u64*)(H01in + arow + (kt << 5));
#pragma unroll
            for (int j = 0; j < 4; j++)
                q[kt][j] = __hip_atomic_load(p + j, __ATOMIC_RELAXED,
                                             __HIP_MEMORY_SCOPE_AGENT);
        }

        // Epilogue gathers (read-only data: normal cached loads, stay warm).
        int ch[4];
#pragma unroll
        for (int r = 0; r < 4; r++) ch[r] = inp[(be + r) * SEQ + t];
        float4v wk[4];
#pragma unroll
        for (int r = 0; r < 4; r++)
            wk[r] = *(const float4v*)&Wkb[(ch[r] << 10) + (u << 2)];

        float4v acc[4];
#pragma unroll
        for (int g = 0; g < 4; g++) acc[g] = (float4v){0.f, 0.f, 0.f, 0.f};

#pragma unroll
        for (int kt = 0; kt < 8; kt++) {
            // unpack packed h -> a0 (lo16 plane), a1 (hi16 plane)
            u32 a0d[4], a1d[4];
#pragma unroll
            for (int d = 0; d < 4; d++) {
                u32 w0 = (u32)(q[kt][d] & 0xffffffffu);
                u32 w1 = (u32)(q[kt][d] >> 32);
                a0d[d] = (w0 & 0xffffu) | (w1 << 16);
                a1d[d] = (w0 >> 16) | (w1 & 0xffff0000u);
            }
            short8 a0, a1;
            ((u32*)&a0)[0] = a0d[0]; ((u32*)&a0)[1] = a0d[1];
            ((u32*)&a0)[2] = a0d[2]; ((u32*)&a0)[3] = a0d[3];
            ((u32*)&a1)[0] = a1d[0]; ((u32*)&a1)[1] = a1d[1];
            ((u32*)&a1)[2] = a1d[2]; ((u32*)&a1)[3] = a1d[3];
#pragma unroll
            for (int g = 0; g < 4; g++) {
                acc[g] = __builtin_amdgcn_mfma_f32_16x16x32_bf16(a0, B0[g][kt], acc[g], 0, 0, 0);
                acc[g] = __builtin_amdgcn_mfma_f32_16x16x32_bf16(a1, B0[g][kt], acc[g], 0, 0, 0);
                acc[g] = __builtin_amdgcn_mfma_f32_16x16x32_bf16(a0, B1[g][kt], acc[g], 0, 0, 0);
            }
        }

        // Epilogue: 4 (batch,unit) states per lane; h out as one packed u32.
#pragma unroll
        for (int r = 0; r < 4; r++) {
            float zi = acc[0][r] + wk[r].x;
            float zf = acc[1][r] + wk[r].y;
            float zg = acc[2][r] + wk[r].z;
            float zo = acc[3][r] + wk[r].w;
            float ig = sigf(zi), fg = sigf(zf), gg = tanhf_(zg), og = sigf(zo);
            float cn = fg * c[r] + ig * gg;
            c[r] = cn;
            float hv = og * tanhf_(cn);
            unsigned short h0 = bf16rne(hv);
            unsigned short h1 = bf16rne(hv - bf16tof(h0));
            u32 packed = (u32)h0 | ((u32)h1 << 16);
            __hip_atomic_store(&H01out[(be + r) * 256 + u], packed,
                               __ATOMIC_RELAXED, __HIP_MEMORY_SCOPE_AGENT);
        }

        // Fence-free row barrier (16 blocks sharing bi).
        if (t != SEQ - 1) {
            __syncthreads();   // compiler drains vmcnt -> h stores complete at L3
            if (tid == 0) {
                __hip_atomic_fetch_add(&ctr[bi], 1u, __ATOMIC_RELAXED,
                                       __HIP_MEMORY_SCOPE_AGENT);
                const u32 target = (u32)(t + 1) * 16u;
                while (__hip_atomic_load(&ctr[bi], __ATOMIC_RELAXED,
                                         __HIP_MEMORY_SCOPE_AGENT) < target)
                    __builtin_amdgcn_s_sleep(1);
            }
            __syncthreads();
        }
    }
}

// ---------------------------------------------------------------------------
// logits = h_last @ dense_w + dense_b ; softmax. h unpacked = lo + hi bf16.
__global__ __launch_bounds__(128) void dense_softmax(
    const u32* __restrict__ H01, const float* __restrict__ W,
    const float* __restrict__ b, float* __restrict__ out)
{
    __shared__ float hsr[UNITS];
    __shared__ float red[NC];
    const int bq = blockIdx.x;
    const int n  = threadIdx.x;

    u32 v0 = H01[bq * 256 + n];
    u32 v1 = H01[bq * 256 + n + 128];
    hsr[n]       = bf16tof((unsigned short)(v0 & 0xffffu)) + bf16tof((unsigned short)(v0 >> 16));
    hsr[n + 128] = bf16tof((unsigned short)(v1 & 0xffffu)) + bf16tof((unsigned short)(v1 >> 16));
    __syncthreads();

    float acc = b[n];
#pragma unroll 8
    for (int k = 0; k < UNITS; k++) acc += hsr[k] * W[k * NC + n];

    red[n] = acc;
    __syncthreads();
    for (int s = 64; s > 0; s >>= 1) {
        if (n < s) red[n] = fmaxf(red[n], red[n + s]);
        __syncthreads();
    }
    float m = red[0];
    __syncthreads();

    float e = __expf(acc - m);
    red[n] = e;
    __syncthreads();
    for (int s = 64; s > 0; s >>= 1) {
        if (n < s) red[n] = red[n] + red[n + s];
        __syncthreads();
    }
    out[bq * NC + n] = e / red[0];
}

// ---------------------------------------------------------------------------
extern "C" void kernel_launch(void* const* d_in, const int* in_sizes, int n_in,
                              void* d_out, int out_size, void* d_ws, size_t ws_size,
                              hipStream_t stream)
{
    const int*   inp  = (const int*)d_in[0];    // [1024][256]
    const float* Wk   = (const float*)d_in[1];  // [128][1024]
    const float* R    = (const float*)d_in[2];  // [256][1024]
    const float* bias = (const float*)d_in[3];  // [1024]
    const float* Wd   = (const float*)d_in[4];  // [256][128]
    const float* bd   = (const float*)d_in[5];  // [128]
    float* out = (float*)d_out;

    // ws: R0t|R1t (512KB ea) | Wkb (512KB) | H01A|H01B (1MB ea) | ctr
    unsigned short* R0t = (unsigned short*)d_ws;
    unsigned short* R1t = R0t + 262144;
    float*          Wkb = (float*)(R1t + 262144);
    u32*            H01A = (u32*)(Wkb + 131072);
    u32*            H01B = H01A + 262144;
    u32*            ctr  = H01B + 262144;

    prep<<<dim3(1024), dim3(256), 0, stream>>>(R, Wk, bias, R0t, R1t, Wkb, H01A, ctr);

    lstm_persist<<<dim3(256), dim3(256), 0, stream>>>(R0t, R1t, Wkb, inp,
                                                      H01A, H01B, ctr);

    // t=255 (odd) wrote H01A
    dense_softmax<<<dim3(BATCH), dim3(128), 0, stream>>>(H01A, Wd, bd, out);
}

// Round 7
// 1743.283 us; speedup vs baseline: 3.2736x; 1.0861x over previous
//
#include <hip/hip_runtime.h>
#include <math.h>

#define BATCH 1024
#define SEQ   256
#define UNITS 256
#define NC    128

typedef __attribute__((ext_vector_type(8))) short  short8;   // 8 bf16 = 4 VGPRs
typedef __attribute__((ext_vector_type(4))) float  float4v;  // MFMA C/D
typedef unsigned long long u64;
typedef unsigned int       u32;

// Gate math (validated r1-r6: absmax 3.05e-5 vs 1.72e-4 threshold)
__device__ __forceinline__ float sigf(float x)  { return 1.f / (1.f + __expf(-x)); }
__device__ __forceinline__ float tanhf_(float x){ return 1.f - 2.f / (1.f + __expf(2.f * x)); }

__device__ __forceinline__ unsigned short bf16rne(float f) {
    unsigned u = __float_as_uint(f);
    return (unsigned short)((u + 0x7fffu + ((u >> 16) & 1u)) >> 16);
}
__device__ __forceinline__ float bf16tof(unsigned short s) {
    return __uint_as_float(((unsigned)s) << 16);
}

// ---------------------------------------------------------------------------
// prep: R0t/R1t[col][k] bf16 split (col = g*256+u, r4-verified layout);
//       Wkb[ch][u*4+g] = Wk + bias (gate-packed); H01A zeroed; flags zeroed.
__global__ __launch_bounds__(256) void prep(
    const float* __restrict__ R, const float* __restrict__ Wk,
    const float* __restrict__ bias,
    unsigned short* __restrict__ R0t, unsigned short* __restrict__ R1t,
    float* __restrict__ Wkb, u32* __restrict__ H01A, u32* __restrict__ flags)
{
    int i = blockIdx.x * 256 + threadIdx.x;    // 0..262143
    int col = i >> 8, k = i & 255;
    float v = R[k * 1024 + col];
    unsigned short r0 = bf16rne(v);
    R0t[i] = r0;
    R1t[i] = bf16rne(v - bf16tof(r0));
    H01A[i] = 0u;                              // h_0 = 0 (packed)
    if (i < NC * 1024) {
        int r = i & 1023;
        int u = r >> 2, g = r & 3;
        int src = (g << 8) + u;
        Wkb[i] = Wk[(i >> 10) * 1024 + src] + bias[src];
    }
    if (i < 16384) flags[i] = 0u;              // 64KB flag region
}

// ---------------------------------------------------------------------------
// Persistent LSTM, wave-autonomous. Grid 256 x 256 thr (all resident -> no
// deadlock). Block (bi=64 batches, ui=16 units); wave wv owns 16 batches.
// R B-frags pinned in VGPRs via asm (remat-blocked) for all 256 steps.
// h packed (h1<<16|h0), exchanged via relaxed agent-scope atomics (L3
// coherent, no fences). Sync: per-wave flag (64B line); producer drains vmcnt
// then stores t+1; consumer's 64 lanes poll the row's 64 wave-flags.
// NO __syncthreads anywhere in the t-loop.
__global__ __launch_bounds__(256, 1) void lstm_persist(
    const unsigned short* __restrict__ R0t, const unsigned short* __restrict__ R1t,
    const float* __restrict__ Wkb, const int* __restrict__ inp,
    u32* __restrict__ H01A, u32* __restrict__ H01B, u32* __restrict__ flags)
{
    const int tid  = threadIdx.x;
    const int lane = tid & 63;
    const int wv   = tid >> 6;                           // 0..3
    const int bi   = ((blockIdx.x & 7) << 1) | (blockIdx.x >> 7);   // 0..15
    const int ui   = (blockIdx.x >> 3) & 15;             // 0..15
    const int nl   = lane & 15;
    const int quad = lane >> 4;
    const int u    = ui * 16 + nl;                       // lane's unit
    const int bm   = bi * 64 + wv * 16;                  // wave's 16-batch base
    const int be   = bm + (quad << 2);                   // lane's 4-batch base

    u32* const fmine = &flags[((bi << 6) + (ui << 2) + wv) << 4];  // 64B stride
    u32* const fpoll = &flags[((bi << 6) + lane) << 4];

    // Load B-frags (r4-verified mapping) then pin: asm output can't be
    // rematerialized, forcing true register residency (~256 VGPR).
    short8 B0[4][8], B1[4][8];
#pragma unroll
    for (int g = 0; g < 4; g++)
#pragma unroll
        for (int kt = 0; kt < 8; kt++) {
            const int idx = ((g << 8) + u) * 256 + (kt << 5) + (quad << 3);
            B0[g][kt] = *(const short8*)&R0t[idx];
            B1[g][kt] = *(const short8*)&R1t[idx];
        }
#pragma unroll
    for (int g = 0; g < 4; g++)
#pragma unroll
        for (int kt = 0; kt < 8; kt++) {
            asm volatile("" : "+v"(B0[g][kt]));
            asm volatile("" : "+v"(B1[g][kt]));
        }

    float c[4] = {0.f, 0.f, 0.f, 0.f};
    const int arow = (bm + nl) * 256 + (quad << 3);      // A-frag u32 base

    int ch[4];
#pragma unroll
    for (int r = 0; r < 4; r++) ch[r] = inp[(be + r) * SEQ];

    for (int t = 0; t < SEQ; t++) {
        const u32* H01in = (t & 1) ? H01B : H01A;
        u32*       H01out = (t & 1) ? H01A : H01B;

        // Issue h-independent loads BEFORE the flag wait so they overlap it.
        float4v wk[4];
#pragma unroll
        for (int r = 0; r < 4; r++)
            wk[r] = *(const float4v*)&Wkb[(ch[r] << 10) + (u << 2)];
        int chn[4];
        if (t != SEQ - 1) {
#pragma unroll
            for (int r = 0; r < 4; r++) chn[r] = inp[(be + r) * SEQ + t + 1];
        }

        // Wait for all 64 producer-waves of this row to have published h_t.
        if (t) {
            const u32 target = (u32)t;
            for (;;) {
                u32 v = __hip_atomic_load(fpoll, __ATOMIC_RELAXED,
                                          __HIP_MEMORY_SCOPE_AGENT);
                if (__ballot(v < target) == 0ull) break;
            }
        }

        // A-frags: 32 atomic u64 loads (device-coherent).
        u64 q[8][4];
#pragma unroll
        for (int kt = 0; kt < 8; kt++) {
            const u64* p = (const u64*)(H01in + arow + (kt << 5));
#pragma unroll
            for (int j = 0; j < 4; j++)
                q[kt][j] = __hip_atomic_load(p + j, __ATOMIC_RELAXED,
                                             __HIP_MEMORY_SCOPE_AGENT);
        }

        float4v acc[4];
#pragma unroll
        for (int g = 0; g < 4; g++) acc[g] = (float4v){0.f, 0.f, 0.f, 0.f};

#pragma unroll
        for (int kt = 0; kt < 8; kt++) {
            u32 a0d[4], a1d[4];
#pragma unroll
            for (int d = 0; d < 4; d++) {
                u32 w0 = (u32)(q[kt][d] & 0xffffffffu);
                u32 w1 = (u32)(q[kt][d] >> 32);
                a0d[d] = (w0 & 0xffffu) | (w1 << 16);
                a1d[d] = (w0 >> 16) | (w1 & 0xffff0000u);
            }
            short8 a0, a1;
            ((u32*)&a0)[0] = a0d[0]; ((u32*)&a0)[1] = a0d[1];
            ((u32*)&a0)[2] = a0d[2]; ((u32*)&a0)[3] = a0d[3];
            ((u32*)&a1)[0] = a1d[0]; ((u32*)&a1)[1] = a1d[1];
            ((u32*)&a1)[2] = a1d[2]; ((u32*)&a1)[3] = a1d[3];
#pragma unroll
            for (int g = 0; g < 4; g++) {
                acc[g] = __builtin_amdgcn_mfma_f32_16x16x32_bf16(a0, B0[g][kt], acc[g], 0, 0, 0);
                acc[g] = __builtin_amdgcn_mfma_f32_16x16x32_bf16(a1, B0[g][kt], acc[g], 0, 0, 0);
                acc[g] = __builtin_amdgcn_mfma_f32_16x16x32_bf16(a0, B1[g][kt], acc[g], 0, 0, 0);
            }
        }

        // Epilogue: 4 (batch,unit) states per lane; h out as one packed u32.
#pragma unroll
        for (int r = 0; r < 4; r++) {
            float zi = acc[0][r] + wk[r].x;
            float zf = acc[1][r] + wk[r].y;
            float zg = acc[2][r] + wk[r].z;
            float zo = acc[3][r] + wk[r].w;
            float ig = sigf(zi), fg = sigf(zf), gg = tanhf_(zg), og = sigf(zo);
            float cn = fg * c[r] + ig * gg;
            c[r] = cn;
            float hv = og * tanhf_(cn);
            unsigned short h0 = bf16rne(hv);
            unsigned short h1 = bf16rne(hv - bf16tof(h0));
            u32 packed = (u32)h0 | ((u32)h1 << 16);
            __hip_atomic_store(&H01out[(be + r) * 256 + u], packed,
                               __ATOMIC_RELAXED, __HIP_MEMORY_SCOPE_AGENT);
        }

        // Publish: drain this wave's stores to the coherence point, then flag.
        if (t != SEQ - 1) {
            __builtin_amdgcn_s_waitcnt(0);
            if (lane == 0)
                __hip_atomic_store(fmine, (u32)(t + 1), __ATOMIC_RELAXED,
                                   __HIP_MEMORY_SCOPE_AGENT);
#pragma unroll
            for (int r = 0; r < 4; r++) ch[r] = chn[r];
        }
    }
}

// ---------------------------------------------------------------------------
// logits = h_last @ dense_w + dense_b ; softmax. h unpacked = lo + hi bf16.
__global__ __launch_bounds__(128) void dense_softmax(
    const u32* __restrict__ H01, const float* __restrict__ W,
    const float* __restrict__ b, float* __restrict__ out)
{
    __shared__ float hsr[UNITS];
    __shared__ float red[NC];
    const int bq = blockIdx.x;
    const int n  = threadIdx.x;

    u32 v0 = H01[bq * 256 + n];
    u32 v1 = H01[bq * 256 + n + 128];
    hsr[n]       = bf16tof((unsigned short)(v0 & 0xffffu)) + bf16tof((unsigned short)(v0 >> 16));
    hsr[n + 128] = bf16tof((unsigned short)(v1 & 0xffffu)) + bf16tof((unsigned short)(v1 >> 16));
    __syncthreads();

    float acc = b[n];
#pragma unroll 8
    for (int k = 0; k < UNITS; k++) acc += hsr[k] * W[k * NC + n];

    red[n] = acc;
    __syncthreads();
    for (int s = 64; s > 0; s >>= 1) {
        if (n < s) red[n] = fmaxf(red[n], red[n + s]);
        __syncthreads();
    }
    float m = red[0];
    __syncthreads();

    float e = __expf(acc - m);
    red[n] = e;
    __syncthreads();
    for (int s = 64; s > 0; s >>= 1) {
        if (n < s) red[n] = red[n] + red[n + s];
        __syncthreads();
    }
    out[bq * NC + n] = e / red[0];
}

// ---------------------------------------------------------------------------
extern "C" void kernel_launch(void* const* d_in, const int* in_sizes, int n_in,
                              void* d_out, int out_size, void* d_ws, size_t ws_size,
                              hipStream_t stream)
{
    const int*   inp  = (const int*)d_in[0];    // [1024][256]
    const float* Wk   = (const float*)d_in[1];  // [128][1024]
    const float* R    = (const float*)d_in[2];  // [256][1024]
    const float* bias = (const float*)d_in[3];  // [1024]
    const float* Wd   = (const float*)d_in[4];  // [256][128]
    const float* bd   = (const float*)d_in[5];  // [128]
    float* out = (float*)d_out;

    // ws: R0t|R1t (512KB ea) | Wkb (512KB) | H01A|H01B (1MB ea) | flags (64KB)
    unsigned short* R0t  = (unsigned short*)d_ws;
    unsigned short* R1t  = R0t + 262144;
    float*          Wkb  = (float*)(R1t + 262144);
    u32*            H01A = (u32*)(Wkb + 131072);
    u32*            H01B = H01A + 262144;
    u32*            flags = H01B + 262144;

    prep<<<dim3(1024), dim3(256), 0, stream>>>(R, Wk, bias, R0t, R1t, Wkb, H01A, flags);

    lstm_persist<<<dim3(256), dim3(256), 0, stream>>>(R0t, R1t, Wkb, inp,
                                                      H01A, H01B, flags);

    // t=255 (odd) wrote H01A
    dense_softmax<<<dim3(BATCH), dim3(128), 0, stream>>>(H01A, Wd, bd, out);
}

// Round 8
// 1180.922 us; speedup vs baseline: 4.8325x; 1.4762x over previous
//
#include <hip/hip_runtime.h>
#include <math.h>

#define BATCH 1024
#define SEQ   256
#define UNITS 256
#define NC    128

typedef __attribute__((ext_vector_type(8))) short  short8;   // 8 bf16 = 4 regs
typedef __attribute__((ext_vector_type(4))) float  float4v;  // MFMA C/D
typedef unsigned long long u64;
typedef unsigned int       u32;

// Gate math (validated r1-r7: absmax 3.05e-5 vs 1.72e-4 threshold)
__device__ __forceinline__ float sigf(float x)  { return 1.f / (1.f + __expf(-x)); }
__device__ __forceinline__ float tanhf_(float x){ return 1.f - 2.f / (1.f + __expf(2.f * x)); }

__device__ __forceinline__ unsigned short bf16rne(float f) {
    unsigned u = __float_as_uint(f);
    return (unsigned short)((u + 0x7fffu + ((u >> 16) & 1u)) >> 16);
}
__device__ __forceinline__ float bf16tof(unsigned short s) {
    return __uint_as_float(((unsigned)s) << 16);
}

// ---------------------------------------------------------------------------
// prep: R0t/R1t[col][k] bf16 split (col = g*256+u, r4-verified layout);
//       Wkb[ch][u*4+g] = Wk + bias (gate-packed); H01A zeroed; ctr zeroed.
__global__ __launch_bounds__(256) void prep(
    const float* __restrict__ R, const float* __restrict__ Wk,
    const float* __restrict__ bias,
    unsigned short* __restrict__ R0t, unsigned short* __restrict__ R1t,
    float* __restrict__ Wkb, u32* __restrict__ H01A, u32* __restrict__ ctr)
{
    int i = blockIdx.x * 256 + threadIdx.x;    // 0..262143
    int col = i >> 8, k = i & 255;
    float v = R[k * 1024 + col];
    unsigned short r0 = bf16rne(v);
    R0t[i] = r0;
    R1t[i] = bf16rne(v - bf16tof(r0));
    H01A[i] = 0u;                              // h_0 = 0 (packed)
    if (i < NC * 1024) {
        int r = i & 1023;
        int u = r >> 2, g = r & 3;
        int src = (g << 8) + u;
        Wkb[i] = Wk[(i >> 10) * 1024 + src] + bias[src];
    }
    if (i < 1024) ctr[i] = 0u;                 // 64 rows x 16-u32 pad
}

// ---------------------------------------------------------------------------
// Persistent LSTM. Grid 256 x 256 thr (1 block/CU, all resident). Block =
// 16 batches (one M-tile) x 64 units: 4 waves side-by-side on units -> sync
// domain is only the 4 blocks sharing a batch row. Per step the block stages
// its row's 16KB h slice ONCE into LDS (pre-unpacked into h0/h1 planes),
// shared by all 4 waves (4x less coherence-point traffic than per-wave
// loads). R B-frags live in exactly 256 AGPRs via inline-asm MFMA with "a"
// constraints (VGPR-side hoist failed r6/r7 at 160-172 VGPR). Sync: one
// 64B-padded counter per row; 4 producers atomicAdd; consumers poll a single
// line with s_sleep backoff (r7's 64-line poll flooded L3).
__global__ __launch_bounds__(256, 1) void lstm_persist(
    const unsigned short* __restrict__ R0t, const unsigned short* __restrict__ R1t,
    const float* __restrict__ Wkb, const int* __restrict__ inp,
    u32* __restrict__ H01A, u32* __restrict__ H01B, u32* __restrict__ ctr)
{
    __shared__ u32 Llo[16 * 132];   // h0 plane, [batch][u32 col] pad +4
    __shared__ u32 Lhi[16 * 132];   // h1 plane

    const int tid  = threadIdx.x;
    const int lane = tid & 63;
    const int wv   = tid >> 6;                              // 0..3
    const int bI   = blockIdx.x;
    // 4 blocks of a row share bI&7 -> same XCD under round-robin (perf-only)
    const int row  = ((bI & 7) << 3) | ((bI >> 3) & 7);     // 0..63
    const int ui   = bI >> 6;                               // 0..3
    const int nl   = lane & 15;
    const int quad = lane >> 4;
    const int u    = ui * 64 + wv * 16 + nl;                // lane's unit
    const int bm   = row * 16;                              // block's 16 batches
    const int be   = bm + (quad << 2);                      // lane's 4-batch base

    u32* const myctr = &ctr[row << 4];                      // 64B-padded line

    // B-frags (r4-verified layout) -> exactly 256 AGPRs, pinned.
    short8 B0[4][8], B1[4][8];
#pragma unroll
    for (int g = 0; g < 4; g++)
#pragma unroll
        for (int kt = 0; kt < 8; kt++) {
            const int idx = ((g << 8) + u) * 256 + (kt << 5) + (quad << 3);
            B0[g][kt] = *(const short8*)&R0t[idx];
            B1[g][kt] = *(const short8*)&R1t[idx];
        }
#pragma unroll
    for (int g = 0; g < 4; g++)
#pragma unroll
        for (int kt = 0; kt < 8; kt++) {
            asm volatile("" : "+a"(B0[g][kt]));
            asm volatile("" : "+a"(B1[g][kt]));
        }

    float c[4] = {0.f, 0.f, 0.f, 0.f};
    int ch[4];
#pragma unroll
    for (int r = 0; r < 4; r++) ch[r] = inp[(be + r) * SEQ];

    for (int t = 0; t < SEQ; t++) {
        const u32* Hin  = (t & 1) ? H01B : H01A;
        u32*       Hout = (t & 1) ? H01A : H01B;

        // h-independent loads issued before the poll so they overlap it.
        float4v wk[4];
#pragma unroll
        for (int r = 0; r < 4; r++)
            wk[r] = *(const float4v*)&Wkb[(ch[r] << 10) + (u << 2)];
        int chn[4];
        if (t != SEQ - 1) {
#pragma unroll
            for (int r = 0; r < 4; r++) chn[r] = inp[(be + r) * SEQ + t + 1];
        }

        // Wait: all 4 blocks of this row published h_t (single-line poll).
        if (t) {
            const u32 target = (u32)(t << 2);
            while (__hip_atomic_load(myctr, __ATOMIC_RELAXED,
                                     __HIP_MEMORY_SCOPE_AGENT) < target)
                __builtin_amdgcn_s_sleep(1);
        }

        // Stage row's h slice (16KB) -> LDS, unpacked to h0/h1 planes.
        {
            const u64* src = (const u64*)(Hin + (bm << 8));  // 2048 u64
#pragma unroll
            for (int i = 0; i < 8; i++) {
                const int e = tid + (i << 8);
                u64 q = __hip_atomic_load(src + e, __ATOMIC_RELAXED,
                                          __HIP_MEMORY_SCOPE_AGENT);
                u32 w0 = (u32)q, w1 = (u32)(q >> 32);
                const int rr = e >> 7, cp = e & 127;
                Llo[rr * 132 + cp] = (w0 & 0xffffu) | (w1 << 16);
                Lhi[rr * 132 + cp] = (w0 >> 16) | (w1 & 0xffff0000u);
            }
        }
        __syncthreads();

        // MFMA loop: A from LDS (shared by all waves), B from AGPRs.
        float4v acc[4];
#pragma unroll
        for (int kt = 0; kt < 8; kt++) {
            short8 a0 = *(const short8*)&Llo[nl * 132 + (kt << 4) + (quad << 2)];
            short8 a1 = *(const short8*)&Lhi[nl * 132 + (kt << 4) + (quad << 2)];
            if (kt == 0) {
#pragma unroll
                for (int g = 0; g < 4; g++) {
                    asm volatile("v_mfma_f32_16x16x32_bf16 %0, %1, %2, 0"
                                 : "=v"(acc[g]) : "v"(a0), "a"(B0[g][0]));
                    asm volatile("v_mfma_f32_16x16x32_bf16 %0, %1, %2, %0"
                                 : "+v"(acc[g]) : "v"(a1), "a"(B0[g][0]));
                    asm volatile("v_mfma_f32_16x16x32_bf16 %0, %1, %2, %0"
                                 : "+v"(acc[g]) : "v"(a0), "a"(B1[g][0]));
                }
            } else {
#pragma unroll
                for (int g = 0; g < 4; g++) {
                    asm volatile("v_mfma_f32_16x16x32_bf16 %0, %1, %2, %0"
                                 : "+v"(acc[g]) : "v"(a0), "a"(B0[g][kt]));
                    asm volatile("v_mfma_f32_16x16x32_bf16 %0, %1, %2, %0"
                                 : "+v"(acc[g]) : "v"(a1), "a"(B0[g][kt]));
                    asm volatile("v_mfma_f32_16x16x32_bf16 %0, %1, %2, %0"
                                 : "+v"(acc[g]) : "v"(a0), "a"(B1[g][kt]));
                }
            }
        }
        // Inline-asm MFMA is opaque to the hazard recognizer: pad the
        // MFMA-write -> VALU-read gap manually before reading acc.
        asm volatile("s_nop 7\n\ts_nop 7\n\ts_nop 3" ::: );

        // Epilogue: 4 (batch,unit) states per lane; h out packed u32.
#pragma unroll
        for (int r = 0; r < 4; r++) {
            float zi = acc[0][r] + wk[r].x;
            float zf = acc[1][r] + wk[r].y;
            float zg = acc[2][r] + wk[r].z;
            float zo = acc[3][r] + wk[r].w;
            float ig = sigf(zi), fg = sigf(zf), gg = tanhf_(zg), og = sigf(zo);
            float cn = fg * c[r] + ig * gg;
            c[r] = cn;
            float hv = og * tanhf_(cn);
            unsigned short h0 = bf16rne(hv);
            unsigned short h1 = bf16rne(hv - bf16tof(h0));
            u32 packed = (u32)h0 | ((u32)h1 << 16);
            __hip_atomic_store(&Hout[(be + r) * 256 + u], packed,
                               __ATOMIC_RELAXED, __HIP_MEMORY_SCOPE_AGENT);
        }

        // Publish: __syncthreads drains every wave's vmcnt (stores at the
        // coherence point), then one RMW per block. Also separates this
        // step's LDS reads from next step's staging writes.
        if (t != SEQ - 1) {
            __syncthreads();
            if (tid == 0)
                __hip_atomic_fetch_add(myctr, 1u, __ATOMIC_RELAXED,
                                       __HIP_MEMORY_SCOPE_AGENT);
#pragma unroll
            for (int r = 0; r < 4; r++) ch[r] = chn[r];
        }
    }
}

// ---------------------------------------------------------------------------
// logits = h_last @ dense_w + dense_b ; softmax. h unpacked = lo + hi bf16.
__global__ __launch_bounds__(128) void dense_softmax(
    const u32* __restrict__ H01, const float* __restrict__ W,
    const float* __restrict__ b, float* __restrict__ out)
{
    __shared__ float hsr[UNITS];
    __shared__ float red[NC];
    const int bq = blockIdx.x;
    const int n  = threadIdx.x;

    u32 v0 = H01[bq * 256 + n];
    u32 v1 = H01[bq * 256 + n + 128];
    hsr[n]       = bf16tof((unsigned short)(v0 & 0xffffu)) + bf16tof((unsigned short)(v0 >> 16));
    hsr[n + 128] = bf16tof((unsigned short)(v1 & 0xffffu)) + bf16tof((unsigned short)(v1 >> 16));
    __syncthreads();

    float acc = b[n];
#pragma unroll 8
    for (int k = 0; k < UNITS; k++) acc += hsr[k] * W[k * NC + n];

    red[n] = acc;
    __syncthreads();
    for (int s = 64; s > 0; s >>= 1) {
        if (n < s) red[n] = fmaxf(red[n], red[n + s]);
        __syncthreads();
    }
    float m = red[0];
    __syncthreads();

    float e = __expf(acc - m);
    red[n] = e;
    __syncthreads();
    for (int s = 64; s > 0; s >>= 1) {
        if (n < s) red[n] = red[n] + red[n + s];
        __syncthreads();
    }
    out[bq * NC + n] = e / red[0];
}

// ---------------------------------------------------------------------------
extern "C" void kernel_launch(void* const* d_in, const int* in_sizes, int n_in,
                              void* d_out, int out_size, void* d_ws, size_t ws_size,
                              hipStream_t stream)
{
    const int*   inp  = (const int*)d_in[0];    // [1024][256]
    const float* Wk   = (const float*)d_in[1];  // [128][1024]
    const float* R    = (const float*)d_in[2];  // [256][1024]
    const float* bias = (const float*)d_in[3];  // [1024]
    const float* Wd   = (const float*)d_in[4];  // [256][128]
    const float* bd   = (const float*)d_in[5];  // [128]
    float* out = (float*)d_out;

    // ws: R0t|R1t (512KB ea) | Wkb (512KB) | H01A|H01B (1MB ea) | ctr (4KB)
    unsigned short* R0t  = (unsigned short*)d_ws;
    unsigned short* R1t  = R0t + 262144;
    float*          Wkb  = (float*)(R1t + 262144);
    u32*            H01A = (u32*)(Wkb + 131072);
    u32*            H01B = H01A + 262144;
    u32*            ctr  = H01B + 262144;

    prep<<<dim3(1024), dim3(256), 0, stream>>>(R, Wk, bias, R0t, R1t, Wkb, H01A, ctr);

    lstm_persist<<<dim3(256), dim3(256), 0, stream>>>(R0t, R1t, Wkb, inp,
                                                      H01A, H01B, ctr);

    // t=255 (odd) wrote H01A
    dense_softmax<<<dim3(BATCH), dim3(128), 0, stream>>>(H01A, Wd, bd, out);
}